// Round 3
// baseline (280.337 us; speedup 1.0000x reference)
//
#include <hip/hip_runtime.h>

#define DIM 128
#define PAD 64

typedef __bf16 bf16x8 __attribute__((ext_vector_type(8)));
typedef float f32x4 __attribute__((ext_vector_type(4)));
typedef unsigned short ushort8 __attribute__((ext_vector_type(8)));

__device__ __forceinline__ unsigned short f2bf(float f) {
    union { float f; unsigned u; } x; x.f = f;
    unsigned r = x.u + 0x7FFF + ((x.u >> 16) & 1);   // RNE
    return (unsigned short)(r >> 16);
}

__device__ __forceinline__ float bf2f(unsigned short u) {
    union { unsigned u; float f; } x; x.u = ((unsigned)u) << 16;
    return x.f;
}

// ---------- fused build: edge scatter (atomic-latency-bound) + conv/pack (streaming,
// hides in the atomic shadow). counts pre-zeroed via hipMemsetAsync.
// R3: col_pad scatter now via atomicExch. R12's hazard was dirty-LINE writeback
// merging from non-coherent per-XCD L2s (normal stores). Atomics execute at the
// device coherent point at 4B granularity -> no local dirty line, no clobber, and
// same-line writes merge memory-side instead of 800K partial-line nt HBM
// transactions (62MB -> ~28MB WRITE_SIZE).
__global__ void build_fused(const int* __restrict__ src, const int* __restrict__ dst,
                            int* __restrict__ counts, int* __restrict__ col_pad,
                            const float* __restrict__ x, unsigned short* __restrict__ xb,
                            const float* __restrict__ W_self, const float* __restrict__ W_neigh,
                            unsigned short* __restrict__ Bp, int E, int n8) {
    int t = blockIdx.x * blockDim.x + threadIdx.x;
    if (t < E) {
        int v = dst[t];
        int pos = atomicAdd(&counts[v], 1);
        if (pos < PAD)
            atomicExch(&col_pad[(size_t)v * PAD + pos], src[t]);
    }
    if (t < n8) {
        const float4* p = (const float4*)(x + (size_t)t * 8);
        float4 a = p[0], b = p[1];
        ushort8 o = {f2bf(a.x), f2bf(a.y), f2bf(a.z), f2bf(a.w),
                     f2bf(b.x), f2bf(b.y), f2bf(b.z), f2bf(b.w)};
        *(ushort8*)(xb + (size_t)t * 8) = o;
    } else if (t < n8 + 3 * 64 * 64) {
        int u = t - n8;
        int lane = u & 63;
        int g = u >> 6;
        int l = g >> 6;
        int r = g & 63;
        int ns = r >> 3, ks = r & 7;
        const float* Wsl = W_self + (size_t)l * DIM * DIM;
        const float* Wnl = W_neigh + (size_t)l * DIM * DIM;
        unsigned short* dstp = Bp + (size_t)l * 32768 + ((size_t)(ns * 8 + ks) * 64 + lane) * 8;
        int nn = ns * 16 + (lane & 15);
        int kbase = ks * 32 + (lane >> 4) * 8;
        ushort8 o;
        #pragma unroll
        for (int j = 0; j < 8; ++j) {
            int k = kbase + j;
            float v = (k < 128) ? Wsl[(size_t)k * DIM + nn] : Wnl[(size_t)(k - 128) * DIM + nn];
            o[j] = f2bf(v);
        }
        *(ushort8*)dstp = o;
    }
}

// ---------- fused layer v3: as v2 (occupancy-first, B from global, 8KB LDS agg
// tile) but gather unrolled to 8 rows in flight per group iteration (two int4
// index loads + 8 masked row loads) to deepen the memory-level parallelism on
// the latency chain. Masked-FMA remainder; garbage indices clamped to a valid
// address before use. ----------
__global__ __launch_bounds__(256, 5) void layer_k(
    const unsigned short* __restrict__ hb,
    const int* __restrict__ counts, const int* __restrict__ col_pad,
    const unsigned short* __restrict__ Bp, const float* __restrict__ bias,
    unsigned short* __restrict__ out_bf, float* __restrict__ out_f32,
    int n, int do_relu)
{
    __shared__ unsigned short ldsA[32 * 128];      // 8192 B: 32 x 128 bf16 agg tile

    const int tid  = threadIdx.x;
    const int w    = tid >> 6;
    const int lane = tid & 63;
    const int li   = lane & 15;    // 16B chunk idx (gather) / output row-in-16 (gemm)
    const int grp  = lane >> 4;    // node slot (gather) / k-quad (gemm)

    const int nb0 = blockIdx.x * 32;

    // ---- gather: each 16-lane group aggregates one node per round, 2 rounds ----
    #pragma unroll
    for (int r = 0; r < 2; ++r) {
        const int row  = w * 8 + r * 4 + grp;      // 0..31 local row
        const int node = nb0 + row;
        const int c    = (node < n) ? counts[node] : 0;
        const int cc   = min(c, PAD);
        const int* cp  = col_pad + (size_t)node * PAD;
        float a[8] = {0.f, 0.f, 0.f, 0.f, 0.f, 0.f, 0.f, 0.f};
        for (int i = 0; i < cc; i += 8) {
            // row is 64 ints; i<=56 so cp[i..i+7] always in-bounds (garbage masked)
            int4 lo = *(const int4*)(cp + i);
            int4 hi = *(const int4*)(cp + i + 4);
            const int rem = cc - i;                // >= 1
            const int u0 = lo.x;
            const int u1 = rem > 1 ? lo.y : u0;    // clamp addr to a valid index
            const int u2 = rem > 2 ? lo.z : u0;
            const int u3 = rem > 3 ? lo.w : u0;
            const int u4 = rem > 4 ? hi.x : u0;
            const int u5 = rem > 5 ? hi.y : u0;
            const int u6 = rem > 6 ? hi.z : u0;
            const int u7 = rem > 7 ? hi.w : u0;
            const float m1 = rem > 1 ? 1.f : 0.f;
            const float m2 = rem > 2 ? 1.f : 0.f;
            const float m3 = rem > 3 ? 1.f : 0.f;
            const float m4 = rem > 4 ? 1.f : 0.f;
            const float m5 = rem > 5 ? 1.f : 0.f;
            const float m6 = rem > 6 ? 1.f : 0.f;
            const float m7 = rem > 7 ? 1.f : 0.f;
            ushort8 v0 = *(const ushort8*)(hb + (size_t)u0 * DIM + li * 8);
            ushort8 v1 = *(const ushort8*)(hb + (size_t)u1 * DIM + li * 8);
            ushort8 v2 = *(const ushort8*)(hb + (size_t)u2 * DIM + li * 8);
            ushort8 v3 = *(const ushort8*)(hb + (size_t)u3 * DIM + li * 8);
            ushort8 v4 = *(const ushort8*)(hb + (size_t)u4 * DIM + li * 8);
            ushort8 v5 = *(const ushort8*)(hb + (size_t)u5 * DIM + li * 8);
            ushort8 v6 = *(const ushort8*)(hb + (size_t)u6 * DIM + li * 8);
            ushort8 v7 = *(const ushort8*)(hb + (size_t)u7 * DIM + li * 8);
            #pragma unroll
            for (int j = 0; j < 8; ++j) {
                float s01 = bf2f(v0[j]) + m1 * bf2f(v1[j]);
                float s23 = m2 * bf2f(v2[j]) + m3 * bf2f(v3[j]);
                float s45 = m4 * bf2f(v4[j]) + m5 * bf2f(v5[j]);
                float s67 = m6 * bf2f(v6[j]) + m7 * bf2f(v7[j]);
                a[j] += (s01 + s23) + (s45 + s67);
            }
        }
        const float s = 1.0f / (float)(c > 0 ? c : 1);
        ushort8 o = {f2bf(a[0] * s), f2bf(a[1] * s), f2bf(a[2] * s), f2bf(a[3] * s),
                     f2bf(a[4] * s), f2bf(a[5] * s), f2bf(a[6] * s), f2bf(a[7] * s)};
        // swizzled store: logical chunk li of row -> slot li ^ (row&7)  (G4/T2)
        *(ushort8*)&ldsA[((size_t)row * 16 + (li ^ (row & 7))) * 8] = o;
    }
    __syncthreads();

    // ---- GEMM: wave w -> 16-row x 64-col quadrant. B frags straight from global
    // (L1/L2-resident, coalesced 1KB per frag per wave). ----
    const int rrow = (w & 1) * 16;                 // local row base
    const int nsb  = (w >> 1) * 4;                 // ns half
    const int row0 = nb0 + rrow;
    int ar = row0 + li;
    if (ar >= n) ar = n - 1;                       // clamp; invalid rows never stored
    const unsigned short* hp = hb + (size_t)ar * DIM + grp * 8;
    const int arow = rrow + li;
    const int sw = arow & 7;

    f32x4 acc[4];
    #pragma unroll
    for (int nsi = 0; nsi < 4; ++nsi) acc[nsi] = (f32x4){0.f, 0.f, 0.f, 0.f};

    #pragma unroll
    for (int ks = 0; ks < 8; ++ks) {
        bf16x8 av;
        if (ks < 4) {
            av = *(const bf16x8*)(hp + ks * 32);
        } else {
            int ch = ((ks - 4) * 4 + grp) ^ sw;    // inverse of the gather swizzle
            av = *(const bf16x8*)&ldsA[((size_t)arow * 16 + ch) * 8];
        }
        #pragma unroll
        for (int nsi = 0; nsi < 4; ++nsi) {
            const int ns = nsb + nsi;
            bf16x8 b = *(const bf16x8*)(Bp + ((size_t)(ns * 8 + ks) * 64 + lane) * 8);
            acc[nsi] = __builtin_amdgcn_mfma_f32_16x16x32_bf16(av, b, acc[nsi], 0, 0, 0);
        }
    }

    #pragma unroll
    for (int nsi = 0; nsi < 4; ++nsi) {
        int col = (nsb + nsi) * 16 + li;
        float bb = bias[col];
        #pragma unroll
        for (int r = 0; r < 4; ++r) {
            int gr = row0 + grp * 4 + r;
            if (gr < n) {
                float v = acc[nsi][r] + bb;
                if (do_relu) v = fmaxf(v, 0.f);
                if (out_bf) out_bf[(size_t)gr * DIM + col] = f2bf(v);
                else        out_f32[(size_t)gr * DIM + col] = v;
            }
        }
    }
}

// ---------- launch ----------

extern "C" void kernel_launch(void* const* d_in, const int* in_sizes, int n_in,
                              void* d_out, int out_size, void* d_ws, size_t ws_size,
                              hipStream_t stream) {
    const float* x      = (const float*)d_in[0];
    const int*   src    = (const int*)d_in[1];
    const int*   dst    = (const int*)d_in[2];
    const float* W_self = (const float*)d_in[3];
    const float* W_neigh= (const float*)d_in[4];
    const float* bias   = (const float*)d_in[5];
    float* out = (float*)d_out;

    const int n = in_sizes[0] / DIM;   // 50000
    const int e = in_sizes[1];         // 800000

    char* ws = (char*)d_ws;
    size_t off = 0;
    auto alloc = [&](size_t bytes) -> void* {
        void* p = ws + off;
        off += (bytes + 255) & ~(size_t)255;
        return p;
    };
    int*   counts  = (int*)alloc((size_t)n * 4);
    int*   col_pad = (int*)alloc((size_t)n * PAD * 4);
    unsigned short* x_bf  = (unsigned short*)alloc((size_t)n * DIM * 2);
    unsigned short* h_a   = (unsigned short*)alloc((size_t)n * DIM * 2);
    unsigned short* h_b   = (unsigned short*)alloc((size_t)n * DIM * 2);
    unsigned short* Bp    = (unsigned short*)alloc((size_t)3 * 32768 * 2);

    const int n8 = n * DIM / 8;         // 800000

    hipMemsetAsync(counts, 0, (size_t)n * 4, stream);
    const int build_units = (e > n8 + 3 * 64 * 64) ? e : (n8 + 3 * 64 * 64);
    build_fused<<<(build_units + 255) / 256, 256, 0, stream>>>(
        src, dst, counts, col_pad, x, x_bf, W_self, W_neigh, Bp, e, n8);

    const int layer_grid = (n + 31) / 32;   // 1563

    layer_k<<<layer_grid, 256, 0, stream>>>(x_bf, counts, col_pad, Bp, bias,
                                            h_a, nullptr, n, 1);
    layer_k<<<layer_grid, 256, 0, stream>>>(h_a, counts, col_pad, Bp + 32768, bias + DIM,
                                            h_b, nullptr, n, 1);
    layer_k<<<layer_grid, 256, 0, stream>>>(h_b, counts, col_pad, Bp + 2 * 32768, bias + 2 * DIM,
                                            nullptr, out, n, 0);
}

// Round 5
// 246.357 us; speedup vs baseline: 1.1379x; 1.1379x over previous
//
#include <hip/hip_runtime.h>

#define DIM 128
#define PAD 64

typedef __bf16 bf16x8 __attribute__((ext_vector_type(8)));
typedef float f32x4 __attribute__((ext_vector_type(4)));
typedef unsigned short ushort8 __attribute__((ext_vector_type(8)));

__device__ __forceinline__ unsigned short f2bf(float f) {
    union { float f; unsigned u; } x; x.f = f;
    unsigned r = x.u + 0x7FFF + ((x.u >> 16) & 1);   // RNE
    return (unsigned short)(r >> 16);
}

__device__ __forceinline__ float bf2f(unsigned short u) {
    union { unsigned u; float f; } x; x.u = ((unsigned)u) << 16;
    return x.f;
}

// ---------- fused build: edge scatter (atomic-latency-bound) + conv/pack (streaming,
// hides in the atomic shadow). counts pre-zeroed via hipMemsetAsync.
// NOTE: nontemporal store REQUIRED for correctness (R12): normal 4B stores to one 64B
// col_pad line from blocks on different XCDs -> partially-dirty non-coherent L2 copies
// -> writeback clobbers other XCDs' bytes. nt bypasses L2 -> byte-granular HBM writes.
// R3 post-mortem: atomicExch did NOT reduce WRITE_SIZE (62MB unchanged) and was
// +16us slower (serialized coherent-point latency). nt store restored.
__global__ void build_fused(const int* __restrict__ src, const int* __restrict__ dst,
                            int* __restrict__ counts, int* __restrict__ col_pad,
                            const float* __restrict__ x, unsigned short* __restrict__ xb,
                            const float* __restrict__ W_self, const float* __restrict__ W_neigh,
                            unsigned short* __restrict__ Bp, int E, int n8) {
    int t = blockIdx.x * blockDim.x + threadIdx.x;
    if (t < E) {
        int v = dst[t];
        int pos = atomicAdd(&counts[v], 1);
        if (pos < PAD)
            __builtin_nontemporal_store(src[t], &col_pad[(size_t)v * PAD + pos]);
    }
    if (t < n8) {
        const float4* p = (const float4*)(x + (size_t)t * 8);
        float4 a = p[0], b = p[1];
        ushort8 o = {f2bf(a.x), f2bf(a.y), f2bf(a.z), f2bf(a.w),
                     f2bf(b.x), f2bf(b.y), f2bf(b.z), f2bf(b.w)};
        *(ushort8*)(xb + (size_t)t * 8) = o;
    } else if (t < n8 + 3 * 64 * 64) {
        int u = t - n8;
        int lane = u & 63;
        int g = u >> 6;
        int l = g >> 6;
        int r = g & 63;
        int ns = r >> 3, ks = r & 7;
        const float* Wsl = W_self + (size_t)l * DIM * DIM;
        const float* Wnl = W_neigh + (size_t)l * DIM * DIM;
        unsigned short* dstp = Bp + (size_t)l * 32768 + ((size_t)(ns * 8 + ks) * 64 + lane) * 8;
        int nn = ns * 16 + (lane & 15);
        int kbase = ks * 32 + (lane >> 4) * 8;
        ushort8 o;
        #pragma unroll
        for (int j = 0; j < 8; ++j) {
            int k = kbase + j;
            float v = (k < 128) ? Wsl[(size_t)k * DIM + nn] : Wnl[(size_t)(k - 128) * DIM + nn];
            o[j] = f2bf(v);
        }
        *(ushort8*)dstp = o;
    }
}

// ---------- fused layer v4: R2's proven structure (4-wide masked gather, B from
// global, XOR-swizzled LDS agg tile) at finer grain: 128-thread block / 16-node
// tile. Grid 3125 ~= 12 blocks/CU of 2-wave quanta -> 24 waves/CU (vs 20), finer
// barrier groups, better tail balance. LDS 4KB. R3's 8-wide unroll reverted
// (+6us/layer: VALU mask overhead + VGPR pressure, no MLP gain). ----------
__global__ __launch_bounds__(128, 6) void layer_k(
    const unsigned short* __restrict__ hb,
    const int* __restrict__ counts, const int* __restrict__ col_pad,
    const unsigned short* __restrict__ Bp, const float* __restrict__ bias,
    unsigned short* __restrict__ out_bf, float* __restrict__ out_f32,
    int n, int do_relu)
{
    __shared__ unsigned short ldsA[16 * 128];      // 4096 B: 16 x 128 bf16 agg tile

    const int tid  = threadIdx.x;
    const int w    = tid >> 6;     // 0..1
    const int lane = tid & 63;
    const int li   = lane & 15;    // 16B chunk idx (gather) / output row-in-16 (gemm)
    const int grp  = lane >> 4;    // node slot (gather) / k-quad (gemm)
    const int g    = w * 4 + grp;  // gather group id 0..7

    const int nb0 = blockIdx.x * 16;

    // ---- gather: each 16-lane group aggregates one node per round, 2 rounds ----
    // group reads full 256B rows (16 lanes x 16B), 4 neighbors per iteration,
    // remainder handled by mask-FMA (indices clamped to a valid in-range value).
    #pragma unroll
    for (int r = 0; r < 2; ++r) {
        const int row  = r * 8 + g;                // 0..15 local row
        const int node = nb0 + row;
        const int c    = (node < n) ? counts[node] : 0;
        const int cc   = min(c, PAD);
        const int* cp  = col_pad + (size_t)node * PAD;
        float a[8] = {0.f, 0.f, 0.f, 0.f, 0.f, 0.f, 0.f, 0.f};
        for (int i = 0; i < cc; i += 4) {
            int4 uu = *(const int4*)(cp + i);
            const int rem = cc - i;                // >= 1
            const float m1 = rem > 1 ? 1.f : 0.f;
            const float m2 = rem > 2 ? 1.f : 0.f;
            const float m3 = rem > 3 ? 1.f : 0.f;
            const int u1 = rem > 1 ? uu.y : uu.x;  // clamp addr to a valid index
            const int u2 = rem > 2 ? uu.z : uu.x;
            const int u3 = rem > 3 ? uu.w : uu.x;
            ushort8 v0 = *(const ushort8*)(hb + (size_t)uu.x * DIM + li * 8);
            ushort8 v1 = *(const ushort8*)(hb + (size_t)u1   * DIM + li * 8);
            ushort8 v2 = *(const ushort8*)(hb + (size_t)u2   * DIM + li * 8);
            ushort8 v3 = *(const ushort8*)(hb + (size_t)u3   * DIM + li * 8);
            #pragma unroll
            for (int j = 0; j < 8; ++j)
                a[j] += (bf2f(v0[j]) + m1 * bf2f(v1[j])) +
                        (m2 * bf2f(v2[j]) + m3 * bf2f(v3[j]));
        }
        const float s = 1.0f / (float)(c > 0 ? c : 1);
        ushort8 o = {f2bf(a[0] * s), f2bf(a[1] * s), f2bf(a[2] * s), f2bf(a[3] * s),
                     f2bf(a[4] * s), f2bf(a[5] * s), f2bf(a[6] * s), f2bf(a[7] * s)};
        // swizzled store: logical chunk li of row -> slot li ^ (row&7)  (G4/T2)
        *(ushort8*)&ldsA[((size_t)row * 16 + (li ^ (row & 7))) * 8] = o;
    }
    __syncthreads();

    // ---- GEMM: wave w -> 16 rows x 64 cols (ns half w). B frags straight from
    // global (L1/L2-resident, coalesced 1KB per frag per wave). ----
    const int nsb  = w * 4;
    const int row0 = nb0;
    int ar = row0 + li;
    if (ar >= n) ar = n - 1;                       // clamp; invalid rows never stored
    const unsigned short* hp = hb + (size_t)ar * DIM + grp * 8;
    const int arow = li;
    const int sw = arow & 7;

    f32x4 acc[4];
    #pragma unroll
    for (int nsi = 0; nsi < 4; ++nsi) acc[nsi] = (f32x4){0.f, 0.f, 0.f, 0.f};

    #pragma unroll
    for (int ks = 0; ks < 8; ++ks) {
        bf16x8 av;
        if (ks < 4) {
            av = *(const bf16x8*)(hp + ks * 32);
        } else {
            int ch = ((ks - 4) * 4 + grp) ^ sw;    // inverse of the gather swizzle
            av = *(const bf16x8*)&ldsA[((size_t)arow * 16 + ch) * 8];
        }
        #pragma unroll
        for (int nsi = 0; nsi < 4; ++nsi) {
            const int ns = nsb + nsi;
            bf16x8 b = *(const bf16x8*)(Bp + ((size_t)(ns * 8 + ks) * 64 + lane) * 8);
            acc[nsi] = __builtin_amdgcn_mfma_f32_16x16x32_bf16(av, b, acc[nsi], 0, 0, 0);
        }
    }

    #pragma unroll
    for (int nsi = 0; nsi < 4; ++nsi) {
        int col = (nsb + nsi) * 16 + li;
        float bb = bias[col];
        #pragma unroll
        for (int r = 0; r < 4; ++r) {
            int gr = row0 + grp * 4 + r;
            if (gr < n) {
                float v = acc[nsi][r] + bb;
                if (do_relu) v = fmaxf(v, 0.f);
                if (out_bf) out_bf[(size_t)gr * DIM + col] = f2bf(v);
                else        out_f32[(size_t)gr * DIM + col] = v;
            }
        }
    }
}

// ---------- launch ----------

extern "C" void kernel_launch(void* const* d_in, const int* in_sizes, int n_in,
                              void* d_out, int out_size, void* d_ws, size_t ws_size,
                              hipStream_t stream) {
    const float* x      = (const float*)d_in[0];
    const int*   src    = (const int*)d_in[1];
    const int*   dst    = (const int*)d_in[2];
    const float* W_self = (const float*)d_in[3];
    const float* W_neigh= (const float*)d_in[4];
    const float* bias   = (const float*)d_in[5];
    float* out = (float*)d_out;

    const int n = in_sizes[0] / DIM;   // 50000
    const int e = in_sizes[1];         // 800000

    char* ws = (char*)d_ws;
    size_t off = 0;
    auto alloc = [&](size_t bytes) -> void* {
        void* p = ws + off;
        off += (bytes + 255) & ~(size_t)255;
        return p;
    };
    int*   counts  = (int*)alloc((size_t)n * 4);
    int*   col_pad = (int*)alloc((size_t)n * PAD * 4);
    unsigned short* x_bf  = (unsigned short*)alloc((size_t)n * DIM * 2);
    unsigned short* h_a   = (unsigned short*)alloc((size_t)n * DIM * 2);
    unsigned short* h_b   = (unsigned short*)alloc((size_t)n * DIM * 2);
    unsigned short* Bp    = (unsigned short*)alloc((size_t)3 * 32768 * 2);

    const int n8 = n * DIM / 8;         // 800000

    hipMemsetAsync(counts, 0, (size_t)n * 4, stream);
    const int build_units = (e > n8 + 3 * 64 * 64) ? e : (n8 + 3 * 64 * 64);
    build_fused<<<(build_units + 255) / 256, 256, 0, stream>>>(
        src, dst, counts, col_pad, x, x_bf, W_self, W_neigh, Bp, e, n8);

    const int layer_grid = (n + 15) / 16;   // 3125

    layer_k<<<layer_grid, 128, 0, stream>>>(x_bf, counts, col_pad, Bp, bias,
                                            h_a, nullptr, n, 1);
    layer_k<<<layer_grid, 128, 0, stream>>>(h_a, counts, col_pad, Bp + 32768, bias + DIM,
                                            h_b, nullptr, n, 1);
    layer_k<<<layer_grid, 128, 0, stream>>>(h_b, counts, col_pad, Bp + 2 * 32768, bias + 2 * DIM,
                                            nullptr, out, n, 0);
}

// Round 7
// 243.527 us; speedup vs baseline: 1.1512x; 1.0116x over previous
//
#include <hip/hip_runtime.h>

#define DIM 128
#define PAD 64

typedef __bf16 bf16x8 __attribute__((ext_vector_type(8)));
typedef float f32x4 __attribute__((ext_vector_type(4)));
typedef unsigned short ushort8 __attribute__((ext_vector_type(8)));

__device__ __forceinline__ unsigned short f2bf(float f) {
    union { float f; unsigned u; } x; x.f = f;
    unsigned r = x.u + 0x7FFF + ((x.u >> 16) & 1);   // RNE
    return (unsigned short)(r >> 16);
}

__device__ __forceinline__ float bf2f(unsigned short u) {
    union { unsigned u; float f; } x; x.u = ((unsigned)u) << 16;
    return x.f;
}

// ---------- fused build: edge scatter (atomic-latency-bound) + conv/pack (streaming,
// hides in the atomic shadow). counts pre-zeroed via hipMemsetAsync.
// NOTE: nontemporal store REQUIRED for correctness (R12): normal 4B stores to one 64B
// col_pad line from blocks on different XCDs -> partially-dirty non-coherent L2 copies
// -> writeback clobbers other XCDs' bytes. nt bypasses L2 -> byte-granular HBM writes.
// R3 post-mortem: atomicExch did NOT reduce WRITE_SIZE (62MB unchanged) and was
// +16us slower (serialized coherent-point latency). nt store restored.
__global__ void build_fused(const int* __restrict__ src, const int* __restrict__ dst,
                            int* __restrict__ counts, int* __restrict__ col_pad,
                            const float* __restrict__ x, unsigned short* __restrict__ xb,
                            const float* __restrict__ W_self, const float* __restrict__ W_neigh,
                            unsigned short* __restrict__ Bp, int E, int n8) {
    int t = blockIdx.x * blockDim.x + threadIdx.x;
    if (t < E) {
        int v = dst[t];
        int pos = atomicAdd(&counts[v], 1);
        if (pos < PAD)
            __builtin_nontemporal_store(src[t], &col_pad[(size_t)v * PAD + pos]);
    }
    if (t < n8) {
        const float4* p = (const float4*)(x + (size_t)t * 8);
        float4 a = p[0], b = p[1];
        ushort8 o = {f2bf(a.x), f2bf(a.y), f2bf(a.z), f2bf(a.w),
                     f2bf(b.x), f2bf(b.y), f2bf(b.z), f2bf(b.w)};
        *(ushort8*)(xb + (size_t)t * 8) = o;
    } else if (t < n8 + 3 * 64 * 64) {
        int u = t - n8;
        int lane = u & 63;
        int g = u >> 6;
        int l = g >> 6;
        int r = g & 63;
        int ns = r >> 3, ks = r & 7;
        const float* Wsl = W_self + (size_t)l * DIM * DIM;
        const float* Wnl = W_neigh + (size_t)l * DIM * DIM;
        unsigned short* dstp = Bp + (size_t)l * 32768 + ((size_t)(ns * 8 + ks) * 64 + lane) * 8;
        int nn = ns * 16 + (lane & 15);
        int kbase = ks * 32 + (lane >> 4) * 8;
        ushort8 o;
        #pragma unroll
        for (int j = 0; j < 8; ++j) {
            int k = kbase + j;
            float v = (k < 128) ? Wsl[(size_t)k * DIM + nn] : Wnl[(size_t)(k - 128) * DIM + nn];
            o[j] = f2bf(v);
        }
        *(ushort8*)dstp = o;
    }
}

// ---------- fused layer v5: v4 geometry (128 thr / 16-node tile, 4-wide masked
// gather, B from global, XOR-swizzled ldsA) + LDS-staged index lists.
// R5 post-mortem: waves 20->24 = 0 gain; R3 MLP 4->8/wave = loss. Model: per-CU
// outstanding-line capacity is the bound (~16 lines per gather instr; ~3.9 TB/s
// cache-side measured = capacity/latency). Lever: MSHR duty cycle. The global
// idx load (200-900cy) on every iteration's address chain leaves zero row-lines
// in flight ~half the time. Staging the block's col_pad slice (4KB, contiguous
// & coalesced) into LDS up front moves the chain to lgkmcnt (~120cy) and keeps
// vmcnt trackers filled with row loads. ----------
__global__ __launch_bounds__(128, 6) void layer_k(
    const unsigned short* __restrict__ hb,
    const int* __restrict__ counts, const int* __restrict__ col_pad,
    const unsigned short* __restrict__ Bp, const float* __restrict__ bias,
    unsigned short* __restrict__ out_bf, float* __restrict__ out_f32,
    int n, int do_relu)
{
    __shared__ int ldsIdx[16 * PAD];               // 4096 B: block's index lists
    __shared__ int ldsCnt[16];
    __shared__ unsigned short ldsA[16 * 128];      // 4096 B: 16 x 128 bf16 agg tile

    const int tid  = threadIdx.x;
    const int w    = tid >> 6;     // 0..1
    const int lane = tid & 63;
    const int li   = lane & 15;    // 16B chunk idx (gather) / output row-in-16 (gemm)
    const int grp  = lane >> 4;    // node slot (gather) / k-quad (gemm)
    const int g    = w * 4 + grp;  // gather group id 0..7

    const int nb0 = blockIdx.x * 16;

    // ---- stage idx lists: 16 nodes x 64 ints = 4KB, contiguous in col_pad ----
    // (over-read past n*PAD for the tail block stays inside the workspace and is
    // gated by c==0, never consumed; n=50000 is a multiple of 16 anyway)
    {
        const int4* s = (const int4*)(col_pad + (size_t)nb0 * PAD);
        int4* d = (int4*)ldsIdx;
        d[tid]       = s[tid];
        d[tid + 128] = s[tid + 128];
    }
    if (tid < 16) {
        const int node = nb0 + tid;
        ldsCnt[tid] = (node < n) ? counts[node] : 0;
    }
    __syncthreads();

    // ---- gather: each 16-lane group aggregates one node per round, 2 rounds ----
    // group reads full 256B rows (16 lanes x 16B), 4 neighbors per iteration,
    // remainder handled by mask-FMA (indices clamped to a valid in-range value).
    #pragma unroll
    for (int r = 0; r < 2; ++r) {
        const int row = r * 8 + g;                 // 0..15 local row
        const int c   = ldsCnt[row];
        const int cc  = min(c, PAD);
        const int* cp = &ldsIdx[row * PAD];        // LDS; group-uniform -> broadcast
        float a[8] = {0.f, 0.f, 0.f, 0.f, 0.f, 0.f, 0.f, 0.f};
        for (int i = 0; i < cc; i += 4) {
            int4 uu = *(const int4*)(cp + i);
            const int rem = cc - i;                // >= 1
            const float m1 = rem > 1 ? 1.f : 0.f;
            const float m2 = rem > 2 ? 1.f : 0.f;
            const float m3 = rem > 3 ? 1.f : 0.f;
            const int u1 = rem > 1 ? uu.y : uu.x;  // clamp addr to a valid index
            const int u2 = rem > 2 ? uu.z : uu.x;
            const int u3 = rem > 3 ? uu.w : uu.x;
            ushort8 v0 = *(const ushort8*)(hb + (size_t)uu.x * DIM + li * 8);
            ushort8 v1 = *(const ushort8*)(hb + (size_t)u1   * DIM + li * 8);
            ushort8 v2 = *(const ushort8*)(hb + (size_t)u2   * DIM + li * 8);
            ushort8 v3 = *(const ushort8*)(hb + (size_t)u3   * DIM + li * 8);
            #pragma unroll
            for (int j = 0; j < 8; ++j)
                a[j] += (bf2f(v0[j]) + m1 * bf2f(v1[j])) +
                        (m2 * bf2f(v2[j]) + m3 * bf2f(v3[j]));
        }
        const float s = 1.0f / (float)(c > 0 ? c : 1);
        ushort8 o = {f2bf(a[0] * s), f2bf(a[1] * s), f2bf(a[2] * s), f2bf(a[3] * s),
                     f2bf(a[4] * s), f2bf(a[5] * s), f2bf(a[6] * s), f2bf(a[7] * s)};
        // swizzled store: logical chunk li of row -> slot li ^ (row&7)  (G4/T2)
        *(ushort8*)&ldsA[((size_t)row * 16 + (li ^ (row & 7))) * 8] = o;
    }
    __syncthreads();

    // ---- GEMM: wave w -> 16 rows x 64 cols (ns half w). B frags straight from
    // global (L2-resident, coalesced 1KB per frag per wave). ----
    const int nsb  = w * 4;
    const int row0 = nb0;
    int ar = row0 + li;
    if (ar >= n) ar = n - 1;                       // clamp; invalid rows never stored
    const unsigned short* hp = hb + (size_t)ar * DIM + grp * 8;
    const int arow = li;
    const int sw = arow & 7;

    f32x4 acc[4];
    #pragma unroll
    for (int nsi = 0; nsi < 4; ++nsi) acc[nsi] = (f32x4){0.f, 0.f, 0.f, 0.f};

    #pragma unroll
    for (int ks = 0; ks < 8; ++ks) {
        bf16x8 av;
        if (ks < 4) {
            av = *(const bf16x8*)(hp + ks * 32);
        } else {
            int ch = ((ks - 4) * 4 + grp) ^ sw;    // inverse of the gather swizzle
            av = *(const bf16x8*)&ldsA[((size_t)arow * 16 + ch) * 8];
        }
        #pragma unroll
        for (int nsi = 0; nsi < 4; ++nsi) {
            const int ns = nsb + nsi;
            bf16x8 b = *(const bf16x8*)(Bp + ((size_t)(ns * 8 + ks) * 64 + lane) * 8);
            acc[nsi] = __builtin_amdgcn_mfma_f32_16x16x32_bf16(av, b, acc[nsi], 0, 0, 0);
        }
    }

    #pragma unroll
    for (int nsi = 0; nsi < 4; ++nsi) {
        int col = (nsb + nsi) * 16 + li;
        float bb = bias[col];
        #pragma unroll
        for (int r = 0; r < 4; ++r) {
            int gr = row0 + grp * 4 + r;
            if (gr < n) {
                float v = acc[nsi][r] + bb;
                if (do_relu) v = fmaxf(v, 0.f);
                if (out_bf) out_bf[(size_t)gr * DIM + col] = f2bf(v);
                else        out_f32[(size_t)gr * DIM + col] = v;
            }
        }
    }
}

// ---------- launch ----------

extern "C" void kernel_launch(void* const* d_in, const int* in_sizes, int n_in,
                              void* d_out, int out_size, void* d_ws, size_t ws_size,
                              hipStream_t stream) {
    const float* x      = (const float*)d_in[0];
    const int*   src    = (const int*)d_in[1];
    const int*   dst    = (const int*)d_in[2];
    const float* W_self = (const float*)d_in[3];
    const float* W_neigh= (const float*)d_in[4];
    const float* bias   = (const float*)d_in[5];
    float* out = (float*)d_out;

    const int n = in_sizes[0] / DIM;   // 50000
    const int e = in_sizes[1];         // 800000

    char* ws = (char*)d_ws;
    size_t off = 0;
    auto alloc = [&](size_t bytes) -> void* {
        void* p = ws + off;
        off += (bytes + 255) & ~(size_t)255;
        return p;
    };
    int*   counts  = (int*)alloc((size_t)n * 4);
    int*   col_pad = (int*)alloc((size_t)n * PAD * 4);
    unsigned short* x_bf  = (unsigned short*)alloc((size_t)n * DIM * 2);
    unsigned short* h_a   = (unsigned short*)alloc((size_t)n * DIM * 2);
    unsigned short* h_b   = (unsigned short*)alloc((size_t)n * DIM * 2);
    unsigned short* Bp    = (unsigned short*)alloc((size_t)3 * 32768 * 2);

    const int n8 = n * DIM / 8;         // 800000

    hipMemsetAsync(counts, 0, (size_t)n * 4, stream);
    const int build_units = (e > n8 + 3 * 64 * 64) ? e : (n8 + 3 * 64 * 64);
    build_fused<<<(build_units + 255) / 256, 256, 0, stream>>>(
        src, dst, counts, col_pad, x, x_bf, W_self, W_neigh, Bp, e, n8);

    const int layer_grid = (n + 15) / 16;   // 3125

    layer_k<<<layer_grid, 128, 0, stream>>>(x_bf, counts, col_pad, Bp, bias,
                                            h_a, nullptr, n, 1);
    layer_k<<<layer_grid, 128, 0, stream>>>(h_a, counts, col_pad, Bp + 32768, bias + DIM,
                                            h_b, nullptr, n, 1);
    layer_k<<<layer_grid, 128, 0, stream>>>(h_b, counts, col_pad, Bp + 2 * 32768, bias + 2 * DIM,
                                            nullptr, out, n, 0);
}